// Round 1
// baseline (704.865 us; speedup 1.0000x reference)
//
#include <hip/hip_runtime.h>

#define SEQ   1024
#define NBATCH 2048
#define INDIM 32
#define HID   12
#define G4    48   // 4*HID

__device__ __forceinline__ float fast_sigmoid(float x) {
    // 1/(1+exp(-x)); __expf -> v_exp_f32-based, ~1ulp. rcp -> v_rcp_f32.
    float e = __expf(-x);
    return __builtin_amdgcn_rcpf(1.0f + e);
}
__device__ __forceinline__ float fast_tanh(float x) {
    // tanh(x) = 2*sigmoid(2x) - 1
    return fmaf(2.0f, fast_sigmoid(2.0f * x), -1.0f);
}

// ---------------------------------------------------------------------------
// Kernel 1: parallel precompute of layer-0 x-part:
//   zx[t*48+j] = bih0[j] + bhh0[j] + sum_k Wih0[j,k] * X[t, 2047, k]
// ---------------------------------------------------------------------------
__global__ __launch_bounds__(256) void lstm_pre(
    const float* __restrict__ X,
    const float* __restrict__ Wih0,
    const float* __restrict__ bih0,
    const float* __restrict__ bhh0,
    float* __restrict__ zx)
{
    int idx = blockIdx.x * blockDim.x + threadIdx.x;   // 0 .. 49151
    int t = idx / G4;
    int j = idx - t * G4;
    if (t >= SEQ) return;
    const float* x = X + (size_t)t * NBATCH * INDIM + (size_t)(NBATCH - 1) * INDIM;
    const float* w = Wih0 + j * INDIM;
    float z = bih0[j] + bhh0[j];
    #pragma unroll
    for (int k = 0; k < INDIM; ++k) z = fmaf(w[k], x[k], z);
    zx[idx] = z;
}

// ---------------------------------------------------------------------------
// Kernel 2: sequential 2-layer LSTM over 1024 steps, single wave of 64.
// Lane j (j<48) owns gate j. Gate order from jnp.split: i(0:12) f(12:24)
// g(24:36) o(36:48). Lane j needs gates (kk, kk+12, kk+24, kk+36), kk=j%12,
// gathered by 4 shuffles; h broadcast back by 12 shuffles.
// ---------------------------------------------------------------------------
__global__ __launch_bounds__(64) void lstm_seq(
    const float* __restrict__ zx,      // [SEQ][48] with bias folded, or null
    const float* __restrict__ X,
    const float* __restrict__ Wih0,
    const float* __restrict__ bih0,
    const float* __restrict__ bhh0,
    const float* __restrict__ Whh0,
    const float* __restrict__ Wih1,
    const float* __restrict__ Whh1,
    const float* __restrict__ bih1,
    const float* __restrict__ bhh1,
    const float* __restrict__ Wfc,
    const float* __restrict__ bfc,
    float* __restrict__ out)
{
    const int j = threadIdx.x;           // 0..63
    const bool active = (j < G4);
    const int jj = active ? j : 0;       // safe index for weight loads
    const int kk = jj % HID;

    // Per-lane gate nonlinearity: a = m * sigmoid(s*z) + d
    // i,f,o -> sigmoid (s=1,m=1,d=0); g (24<=j<36) -> tanh (s=2,m=2,d=-1)
    const bool isg = (j >= 2 * HID) && (j < 3 * HID);
    const float gs = isg ? 2.0f : 1.0f;
    const float gm = isg ? 2.0f : 1.0f;
    const float gd = isg ? -1.0f : 0.0f;

    // Preload per-gate weight rows into registers (constant-index only).
    float whh0[HID], wih1[HID], whh1[HID];
    #pragma unroll
    for (int k = 0; k < HID; ++k) {
        whh0[k] = Whh0[jj * HID + k];
        wih1[k] = Wih1[jj * HID + k];
        whh1[k] = Whh1[jj * HID + k];
    }
    const float b1 = bih1[jj] + bhh1[jj];

    // Fallback path (no precomputed zx): layer-0 input weights + bias.
    float wih0[INDIM];
    float b0 = 0.0f;
    if (zx == nullptr) {
        #pragma unroll
        for (int k = 0; k < INDIM; ++k) wih0[k] = Wih0[jj * INDIM + k];
        b0 = bih0[jj] + bhh0[jj];
    }

    float wfc[HID];
    #pragma unroll
    for (int k = 0; k < HID; ++k) wfc[k] = Wfc[k];
    const float bias_fc = bfc[0];

    // State: h vectors replicated in every lane; c replicated per kk.
    float h0v[HID], h1v[HID];
    #pragma unroll
    for (int k = 0; k < HID; ++k) { h0v[k] = 0.0f; h1v[k] = 0.0f; }
    float c0 = 0.0f, c1 = 0.0f;

    for (int t = 0; t < SEQ; ++t) {
        // ----- layer 0 gate pre-activation -----
        float z0;
        if (zx != nullptr) {
            z0 = active ? zx[t * G4 + j] : 0.0f;
        } else {
            const float* x = X + (size_t)t * NBATCH * INDIM
                               + (size_t)(NBATCH - 1) * INDIM;
            z0 = b0;
            #pragma unroll
            for (int k = 0; k < INDIM; ++k) z0 = fmaf(wih0[k], x[k], z0);
        }
        #pragma unroll
        for (int k = 0; k < HID; ++k) z0 = fmaf(whh0[k], h0v[k], z0);

        float a0 = fmaf(gm, fast_sigmoid(gs * z0), gd);

        float ai = __shfl(a0, kk);
        float af = __shfl(a0, kk + HID);
        float ag = __shfl(a0, kk + 2 * HID);
        float ao = __shfl(a0, kk + 3 * HID);
        c0 = fmaf(af, c0, ai * ag);
        float h0 = ao * fast_tanh(c0);
        #pragma unroll
        for (int k = 0; k < HID; ++k) h0v[k] = __shfl(h0, k);

        // ----- layer 1 -----
        float z1 = b1;
        #pragma unroll
        for (int k = 0; k < HID; ++k) z1 = fmaf(wih1[k], h0v[k], z1);
        #pragma unroll
        for (int k = 0; k < HID; ++k) z1 = fmaf(whh1[k], h1v[k], z1);

        float a1 = fmaf(gm, fast_sigmoid(gs * z1), gd);

        ai = __shfl(a1, kk);
        af = __shfl(a1, kk + HID);
        ag = __shfl(a1, kk + 2 * HID);
        ao = __shfl(a1, kk + 3 * HID);
        c1 = fmaf(af, c1, ai * ag);
        float h1 = ao * fast_tanh(c1);
        #pragma unroll
        for (int k = 0; k < HID; ++k) h1v[k] = __shfl(h1, k);

        // ----- FC head: out[t] = Wfc . h1 + bfc -----
        float o = bias_fc;
        #pragma unroll
        for (int k = 0; k < HID; ++k) o = fmaf(wfc[k], h1v[k], o);
        if (j == 0) out[t] = o;
    }
}

extern "C" void kernel_launch(void* const* d_in, const int* in_sizes, int n_in,
                              void* d_out, int out_size, void* d_ws, size_t ws_size,
                              hipStream_t stream) {
    const float* X    = (const float*)d_in[0];
    const float* Wih0 = (const float*)d_in[1];
    const float* Whh0 = (const float*)d_in[2];
    const float* bih0 = (const float*)d_in[3];
    const float* bhh0 = (const float*)d_in[4];
    const float* Wih1 = (const float*)d_in[5];
    const float* Whh1 = (const float*)d_in[6];
    const float* bih1 = (const float*)d_in[7];
    const float* bhh1 = (const float*)d_in[8];
    const float* Wfc  = (const float*)d_in[9];
    const float* bfc  = (const float*)d_in[10];
    float* out = (float*)d_out;

    const size_t need = (size_t)SEQ * G4 * sizeof(float);
    const float* zx = nullptr;
    if (ws_size >= need) {
        float* zbuf = (float*)d_ws;
        lstm_pre<<<(SEQ * G4 + 255) / 256, 256, 0, stream>>>(X, Wih0, bih0, bhh0, zbuf);
        zx = zbuf;
    }
    lstm_seq<<<1, 64, 0, stream>>>(zx, X, Wih0, bih0, bhh0, Whh0,
                                   Wih1, Whh1, bih1, bhh1, Wfc, bfc, out);
}

// Round 2
// 299.732 us; speedup vs baseline: 2.3516x; 2.3516x over previous
//
#include <hip/hip_runtime.h>

#define SEQ    1024
#define NBATCH 2048
#define INDIM  32
#define HID    12
#define G4     48   // 4*HID

#define LOG2E 1.4426950408889634f

// ---- low-latency cross-lane primitives ------------------------------------
// quad_perm DPP broadcast of lane L (within each group of 4): ctrl = L*0x55
template<int CTRL>
__device__ __forceinline__ float qbcast(float v) {
    int x = __builtin_amdgcn_update_dpp(
        0, __builtin_bit_cast(int, v), CTRL, 0xF, 0xF, true);
    return __builtin_bit_cast(float, x);
}
__device__ __forceinline__ float lanebcast(float v, int lane) {
    return __builtin_bit_cast(float,
        __builtin_amdgcn_readlane(__builtin_bit_cast(int, v), lane));
}

// ---------------------------------------------------------------------------
// Kernel 1: parallel precompute of layer-0 x-part, bias folded, interleaved
// lane layout: zx[t*48 + (4*k+g)] = b[r] + Wih0[r,:]·X[t,2047,:], r = g*12+k.
// Row t==SEQ is a zero pad row (read by the prefetch of the last step).
// ---------------------------------------------------------------------------
__global__ __launch_bounds__(256) void lstm_pre(
    const float* __restrict__ X,
    const float* __restrict__ Wih0,
    const float* __restrict__ bih0,
    const float* __restrict__ bhh0,
    float* __restrict__ zx)
{
    int idx = blockIdx.x * blockDim.x + threadIdx.x;   // 0 .. (SEQ+1)*48-1
    int t = idx / G4;
    int j = idx - t * G4;
    if (t > SEQ) return;
    if (t == SEQ) { zx[idx] = 0.0f; return; }
    int g = j & 3, k = j >> 2;
    int r = g * HID + k;
    const float* x = X + (size_t)t * NBATCH * INDIM + (size_t)(NBATCH - 1) * INDIM;
    const float* w = Wih0 + r * INDIM;
    float za = bih0[r] + bhh0[r], zb = 0.0f;
    #pragma unroll
    for (int kk = 0; kk < INDIM; kk += 2) {
        za = fmaf(w[kk],     x[kk],     za);
        zb = fmaf(w[kk + 1], x[kk + 1], zb);
    }
    zx[idx] = za + zb;
}

// ---------------------------------------------------------------------------
// Kernel 2: sequential 2-layer LSTM, single wave. Lane = 4*unit + gate.
// Gate gather: DPP quad broadcasts. h broadcast: v_readlane -> SGPR operands.
// Layers software-pipelined: body(t) = L0(t) || L1(t-1).
// ---------------------------------------------------------------------------
template<bool USE_WS>
__global__ __launch_bounds__(64) void lstm_seq(
    const float* __restrict__ zx,      // [SEQ+1][48], bias folded (USE_WS)
    float* __restrict__ hbuf,          // [SEQ][12] h1 per step (USE_WS)
    const float* __restrict__ X,
    const float* __restrict__ Wih0,
    const float* __restrict__ bih0,
    const float* __restrict__ bhh0,
    const float* __restrict__ Whh0,
    const float* __restrict__ Wih1,
    const float* __restrict__ Whh1,
    const float* __restrict__ bih1,
    const float* __restrict__ bhh1,
    const float* __restrict__ Wfc,
    const float* __restrict__ bfc,
    float* __restrict__ out)
{
    const int j  = threadIdx.x;            // 0..63
    const int jj = (j < G4) ? j : 0;       // safe clone for lanes 48-63
    const int g  = jj & 3;                 // gate: 0=i 1=f 2=g 3=o
    const int k  = jj >> 2;                // hidden unit 0..11
    const int r  = g * HID + k;            // weight row

    // unified nonlinearity a = gm * rcp(1 + exp2(cexp*z)) + gd
    const bool  isg  = (g == 2);
    const float cexp = isg ? (-2.0f * LOG2E) : (-LOG2E);
    const float gm   = isg ? 2.0f : 1.0f;
    const float gd   = isg ? -1.0f : 0.0f;

    float whh0[HID], wih1[HID], whh1[HID];
    #pragma unroll
    for (int kk = 0; kk < HID; ++kk) {
        whh0[kk] = Whh0[r * HID + kk];
        wih1[kk] = Wih1[r * HID + kk];
        whh1[kk] = Whh1[r * HID + kk];
    }
    const float b1 = bih1[r] + bhh1[r];

    float wih0[INDIM]; float b0 = 0.0f; float wfc[HID]; float bias_fc = 0.0f;
    if constexpr (!USE_WS) {
        #pragma unroll
        for (int kk = 0; kk < INDIM; ++kk) wih0[kk] = Wih0[r * INDIM + kk];
        b0 = bih0[r] + bhh0[r];
        #pragma unroll
        for (int kk = 0; kk < HID; ++kk) wfc[kk] = Wfc[kk];
        bias_fc = bfc[0];
    }

    float s_h0[HID], s_h1[HID];
    #pragma unroll
    for (int kk = 0; kk < HID; ++kk) { s_h0[kk] = 0.0f; s_h1[kk] = 0.0f; }
    float c0 = 0.0f, c1 = 0.0f;

    auto act = [&](float z) {
        float e  = __builtin_amdgcn_exp2f(z * cexp);
        float rr = __builtin_amdgcn_rcpf(1.0f + e);
        return fmaf(gm, rr, gd);
    };

    // fallback: compute layer-0 x-part in-loop
    auto xpart = [&](int t) {
        const float* x = X + (size_t)t * NBATCH * INDIM
                           + (size_t)(NBATCH - 1) * INDIM;
        float za = b0, zb = 0.0f;
        #pragma unroll
        for (int kk = 0; kk < INDIM; kk += 2) {
            za = fmaf(wih0[kk],     x[kk],     za);
            zb = fmaf(wih0[kk + 1], x[kk + 1], zb);
        }
        return za + zb;
    };

    // full layer-0 step: consumes s_h0(t-1), produces s_h0(t), updates c0
    auto l0_step = [&](float zxv) {
        float za = zxv, zb = 0.0f, zc = 0.0f;
        #pragma unroll
        for (int kk = 0; kk < HID; kk += 3) {
            za = fmaf(whh0[kk],     s_h0[kk],     za);
            zb = fmaf(whh0[kk + 1], s_h0[kk + 1], zb);
            zc = fmaf(whh0[kk + 2], s_h0[kk + 2], zc);
        }
        float a  = act((za + zb) + zc);
        float ai = qbcast<0x00>(a);
        float af = qbcast<0x55>(a);
        float ag = qbcast<0xAA>(a);
        float ao = qbcast<0xFF>(a);
        c0 = fmaf(af, c0, ai * ag);
        float e  = __builtin_amdgcn_exp2f(c0 * (-2.0f * LOG2E));
        float rr = __builtin_amdgcn_rcpf(1.0f + e);
        float h0 = fmaf(ao + ao, rr, -ao);     // o * tanh(c)
        #pragma unroll
        for (int kk = 0; kk < HID; ++kk) s_h0[kk] = lanebcast(h0, 4 * kk);
    };

    // layer-1 z pre-activation: must read s_h0/s_h1 BEFORE they are updated
    auto l1_z = [&]() {
        float ya = b1, yb = 0.0f, yc = 0.0f, yd = 0.0f;
        #pragma unroll
        for (int kk = 0; kk < HID; kk += 2) {
            ya = fmaf(wih1[kk],     s_h0[kk],     ya);
            yb = fmaf(wih1[kk + 1], s_h0[kk + 1], yb);
            yc = fmaf(whh1[kk],     s_h1[kk],     yc);
            yd = fmaf(whh1[kk + 1], s_h1[kk + 1], yd);
        }
        return (ya + yb) + (yc + yd);
    };

    auto l1_fin = [&](float z1, int tm1) {
        float a  = act(z1);
        float ai = qbcast<0x00>(a);
        float af = qbcast<0x55>(a);
        float ag = qbcast<0xAA>(a);
        float ao = qbcast<0xFF>(a);
        c1 = fmaf(af, c1, ai * ag);
        float e  = __builtin_amdgcn_exp2f(c1 * (-2.0f * LOG2E));
        float rr = __builtin_amdgcn_rcpf(1.0f + e);
        float h1 = fmaf(ao + ao, rr, -ao);
        if constexpr (USE_WS) {
            if (j < G4 && g == 0) hbuf[tm1 * HID + k] = h1;
        }
        #pragma unroll
        for (int kk = 0; kk < HID; ++kk) s_h1[kk] = lanebcast(h1, 4 * kk);
        if constexpr (!USE_WS) {
            float o = bias_fc;
            #pragma unroll
            for (int kk = 0; kk < HID; ++kk) o = fmaf(wfc[kk], s_h1[kk], o);
            if (j == 0) out[tm1] = o;
        }
    };

    // prologue: t = 0, layer 0 only
    float zxv;
    if constexpr (USE_WS) zxv = zx[jj];
    else                  zxv = xpart(0);
    l0_step(zxv);
    if constexpr (USE_WS) zxv = zx[G4 + jj];
    else                  zxv = xpart(1);

    for (int t = 1; t < SEQ; ++t) {
        // prefetch next step's layer-0 x-part (row SEQ is the zero pad)
        float zxn;
        if constexpr (USE_WS) zxn = zx[(t + 1) * G4 + jj];
        else                  zxn = 0.0f;   // computed below instead
        float z1 = l1_z();       // reads OLD s_h0, s_h1
        l0_step(zxv);            // updates s_h0, c0
        l1_fin(z1, t - 1);       // updates s_h1, c1; emits h1(t-1)
        if constexpr (USE_WS) zxv = zxn;
        else                  zxv = (t + 1 < SEQ) ? xpart(t + 1) : 0.0f;
    }
    // epilogue: layer 1 for t = SEQ-1
    {
        float z1 = l1_z();
        l1_fin(z1, SEQ - 1);
    }
}

// ---------------------------------------------------------------------------
// Kernel 3: FC head, parallel over t: out[t] = bfc + Wfc . h1(t)
// ---------------------------------------------------------------------------
__global__ __launch_bounds__(256) void fc_head(
    const float* __restrict__ hbuf,
    const float* __restrict__ Wfc,
    const float* __restrict__ bfc,
    float* __restrict__ out)
{
    int t = blockIdx.x * blockDim.x + threadIdx.x;
    if (t >= SEQ) return;
    float o = bfc[0];
    const float* h = hbuf + t * HID;
    #pragma unroll
    for (int kk = 0; kk < HID; ++kk) o = fmaf(Wfc[kk], h[kk], o);
    out[t] = o;
}

extern "C" void kernel_launch(void* const* d_in, const int* in_sizes, int n_in,
                              void* d_out, int out_size, void* d_ws, size_t ws_size,
                              hipStream_t stream) {
    const float* X    = (const float*)d_in[0];
    const float* Wih0 = (const float*)d_in[1];
    const float* Whh0 = (const float*)d_in[2];
    const float* bih0 = (const float*)d_in[3];
    const float* bhh0 = (const float*)d_in[4];
    const float* Wih1 = (const float*)d_in[5];
    const float* Whh1 = (const float*)d_in[6];
    const float* bih1 = (const float*)d_in[7];
    const float* bhh1 = (const float*)d_in[8];
    const float* Wfc  = (const float*)d_in[9];
    const float* bfc  = (const float*)d_in[10];
    float* out = (float*)d_out;

    const size_t zx_floats = (size_t)(SEQ + 1) * G4;
    const size_t need = (zx_floats + (size_t)SEQ * HID) * sizeof(float);
    if (ws_size >= need) {
        float* zbuf = (float*)d_ws;
        float* hbuf = zbuf + zx_floats;
        lstm_pre<<<((SEQ + 1) * G4 + 255) / 256, 256, 0, stream>>>(
            X, Wih0, bih0, bhh0, zbuf);
        lstm_seq<true><<<1, 64, 0, stream>>>(
            zbuf, hbuf, X, Wih0, bih0, bhh0, Whh0,
            Wih1, Whh1, bih1, bhh1, Wfc, bfc, out);
        fc_head<<<(SEQ + 255) / 256, 256, 0, stream>>>(hbuf, Wfc, bfc, out);
    } else {
        lstm_seq<false><<<1, 64, 0, stream>>>(
            nullptr, nullptr, X, Wih0, bih0, bhh0, Whh0,
            Wih1, Whh1, bih1, bhh1, Wfc, bfc, out);
    }
}

// Round 3
// 210.613 us; speedup vs baseline: 3.3467x; 1.4231x over previous
//
#include <hip/hip_runtime.h>

#define SEQ    1024
#define NBATCH 2048
#define INDIM  32
#define HID    12
#define G4     48          // 4*HID
#define NB     (SEQ / 4)   // float4 blocks of 4 timesteps

#define LOG2E 1.4426950408889634f

typedef float f32x2 __attribute__((ext_vector_type(2)));
typedef float f32x4 __attribute__((ext_vector_type(4)));

// ---- low-latency cross-lane primitives ------------------------------------
template<int CTRL>
__device__ __forceinline__ float qbcast(float v) {
    int x = __builtin_amdgcn_update_dpp(
        0, __builtin_bit_cast(int, v), CTRL, 0xF, 0xF, true);
    return __builtin_bit_cast(float, x);
}
__device__ __forceinline__ float lanebcast(float v, int lane) {
    return __builtin_bit_cast(float,
        __builtin_amdgcn_readlane(__builtin_bit_cast(int, v), lane));
}

// ---------------------------------------------------------------------------
// Kernel 1: layer-0 x-part, bias folded, blocked layout:
//   zx[b*192 + j*4 + q] = b[r] + Wih0[r,:]·X[t,2047,:],  t = 4b+q,
//   j = 4*k+g (interleaved lane layout), r = g*12+k.
// Blocks b in [0, NB+2); t >= SEQ rows zeroed (prefetch pads).
// ---------------------------------------------------------------------------
__global__ __launch_bounds__(256) void lstm_pre(
    const float* __restrict__ X,
    const float* __restrict__ Wih0,
    const float* __restrict__ bih0,
    const float* __restrict__ bhh0,
    float* __restrict__ zx)
{
    int idx = blockIdx.x * blockDim.x + threadIdx.x;   // 0 .. (NB+2)*192-1
    if (idx >= (NB + 2) * 192) return;
    int b   = idx / 192;
    int rem = idx - b * 192;
    int j   = rem >> 2;
    int q   = rem & 3;
    int t   = 4 * b + q;
    if (t >= SEQ) { zx[idx] = 0.0f; return; }
    int g = j & 3, k = j >> 2;
    int r = g * HID + k;
    const float* x = X + (size_t)t * NBATCH * INDIM + (size_t)(NBATCH - 1) * INDIM;
    const float* w = Wih0 + r * INDIM;
    float za = bih0[r] + bhh0[r], zb = 0.0f;
    #pragma unroll
    for (int kk = 0; kk < INDIM; kk += 2) {
        za = fmaf(w[kk],     x[kk],     za);
        zb = fmaf(w[kk + 1], x[kk + 1], zb);
    }
    zx[idx] = za + zb;
}

// ---------------------------------------------------------------------------
// Kernel 2: sequential 2-layer LSTM, single wave. Lane = 4*unit + gate.
// Gate gather: DPP quad broadcasts of the raw sigmoid rr (affine folded into
// c/h updates). h broadcast: v_readlane into packed f32x2. zx: float4-block
// rolling prefetch, 2 blocks (8 steps) ahead.
// ---------------------------------------------------------------------------
template<bool USE_WS>
__global__ __launch_bounds__(64) void lstm_seq(
    const f32x4* __restrict__ zx4,     // [(NB+2)][48] float4 (USE_WS)
    float* __restrict__ hbuf,          // [SEQ][12] h1 per step (USE_WS)
    const float* __restrict__ X,
    const float* __restrict__ Wih0,
    const float* __restrict__ bih0,
    const float* __restrict__ bhh0,
    const float* __restrict__ Whh0,
    const float* __restrict__ Wih1,
    const float* __restrict__ Whh1,
    const float* __restrict__ bih1,
    const float* __restrict__ bhh1,
    const float* __restrict__ Wfc,
    const float* __restrict__ bfc,
    float* __restrict__ out)
{
    const int j  = threadIdx.x;            // 0..63
    const int jj = (j < G4) ? j : 0;       // safe clone for lanes 48-63
    const int g  = jj & 3;                 // gate: 0=i 1=f 2=g 3=o
    const int k  = jj >> 2;                // hidden unit 0..11
    const int r  = g * HID + k;            // weight row

    // g-gate computes sigmoid(2z) (tanh affine folded downstream)
    const float cexp = (g == 2) ? (-2.0f * LOG2E) : (-LOG2E);

    // packed per-gate weight rows
    f32x2 wh0p[HID / 2], wi1p[HID / 2], wh1p[HID / 2];
    #pragma unroll
    for (int kk = 0; kk < HID / 2; ++kk) {
        wh0p[kk] = f32x2{Whh0[r * HID + 2 * kk], Whh0[r * HID + 2 * kk + 1]};
        wi1p[kk] = f32x2{Wih1[r * HID + 2 * kk], Wih1[r * HID + 2 * kk + 1]};
        wh1p[kk] = f32x2{Whh1[r * HID + 2 * kk], Whh1[r * HID + 2 * kk + 1]};
    }
    const float b1 = bih1[r] + bhh1[r];

    float wih0[INDIM]; float b0 = 0.0f; float wfc[HID]; float bias_fc = 0.0f;
    if constexpr (!USE_WS) {
        #pragma unroll
        for (int kk = 0; kk < INDIM; ++kk) wih0[kk] = Wih0[r * INDIM + kk];
        b0 = bih0[r] + bhh0[r];
        #pragma unroll
        for (int kk = 0; kk < HID; ++kk) wfc[kk] = Wfc[kk];
        bias_fc = bfc[0];
    }

    // packed h state (uniform values; compiler may keep in SGPRs)
    f32x2 ph0[HID / 2], ph1[HID / 2];
    #pragma unroll
    for (int kk = 0; kk < HID / 2; ++kk) { ph0[kk] = f32x2{0.f, 0.f}; ph1[kk] = f32x2{0.f, 0.f}; }
    float c0 = 0.0f, c1 = 0.0f;

    // fallback: compute layer-0 x-part in-loop
    auto xpart = [&](int t) {
        const float* x = X + (size_t)t * NBATCH * INDIM
                           + (size_t)(NBATCH - 1) * INDIM;
        float za = b0, zb = 0.0f;
        #pragma unroll
        for (int kk = 0; kk < INDIM; kk += 2) {
            za = fmaf(wih0[kk],     x[kk],     za);
            zb = fmaf(wih0[kk + 1], x[kk + 1], zb);
        }
        return za + zb;
    };

    // layer-0 step: consumes ph0(t-1), produces ph0(t), updates c0
    auto l0_step = [&](float zxv) {
        f32x2 a0 = f32x2{zxv, 0.f}, a1 = f32x2{0.f, 0.f};
        #pragma unroll
        for (int kk = 0; kk < HID / 2; kk += 2) {
            a0 = __builtin_elementwise_fma(wh0p[kk],     ph0[kk],     a0);
            a1 = __builtin_elementwise_fma(wh0p[kk + 1], ph0[kk + 1], a1);
        }
        float z0 = (a0.x + a1.x) + (a0.y + a1.y);
        float e  = __builtin_amdgcn_exp2f(z0 * cexp);
        float rr = __builtin_amdgcn_rcpf(1.0f + e);
        float ai = qbcast<0x00>(rr);
        float af = qbcast<0x55>(rr);
        float ag = qbcast<0xAA>(rr);      // sigmoid(2*z_g); tanh = 2*ag-1
        float ao = qbcast<0xFF>(rr);
        c0 = fmaf(af, c0, fmaf(ai + ai, ag, -ai));
        float e2 = __builtin_amdgcn_exp2f(c0 * (-2.0f * LOG2E));
        float rt = __builtin_amdgcn_rcpf(1.0f + e2);
        float h0 = fmaf(ao + ao, rt, -ao);          // o * tanh(c0)
        #pragma unroll
        for (int kk = 0; kk < HID / 2; ++kk) {
            ph0[kk].x = lanebcast(h0, 8 * kk);
            ph0[kk].y = lanebcast(h0, 8 * kk + 4);
        }
    };

    // layer-1 pre-activation: reads OLD ph0/ph1
    auto l1_z = [&]() {
        f32x2 a0 = f32x2{b1, 0.f}, a1 = f32x2{0.f, 0.f};
        #pragma unroll
        for (int kk = 0; kk < HID / 2; kk += 2) {
            a0 = __builtin_elementwise_fma(wi1p[kk],     ph0[kk],     a0);
            a1 = __builtin_elementwise_fma(wi1p[kk + 1], ph0[kk + 1], a1);
            a0 = __builtin_elementwise_fma(wh1p[kk],     ph1[kk],     a0);
            a1 = __builtin_elementwise_fma(wh1p[kk + 1], ph1[kk + 1], a1);
        }
        return (a0.x + a1.x) + (a0.y + a1.y);
    };

    auto l1_fin = [&](float z1, int tm1) {
        float e  = __builtin_amdgcn_exp2f(z1 * cexp);
        float rr = __builtin_amdgcn_rcpf(1.0f + e);
        float ai = qbcast<0x00>(rr);
        float af = qbcast<0x55>(rr);
        float ag = qbcast<0xAA>(rr);
        float ao = qbcast<0xFF>(rr);
        c1 = fmaf(af, c1, fmaf(ai + ai, ag, -ai));
        float e2 = __builtin_amdgcn_exp2f(c1 * (-2.0f * LOG2E));
        float rt = __builtin_amdgcn_rcpf(1.0f + e2);
        float h1 = fmaf(ao + ao, rt, -ao);
        if constexpr (USE_WS) {
            if (j < G4 && g == 0) hbuf[tm1 * HID + k] = h1;
        }
        #pragma unroll
        for (int kk = 0; kk < HID / 2; ++kk) {
            ph1[kk].x = lanebcast(h1, 8 * kk);
            ph1[kk].y = lanebcast(h1, 8 * kk + 4);
        }
        if constexpr (!USE_WS) {
            float o = bias_fc;
            #pragma unroll
            for (int kk = 0; kk < HID / 2; ++kk) {
                o = fmaf(wfc[2 * kk],     ph1[kk].x, o);
                o = fmaf(wfc[2 * kk + 1], ph1[kk].y, o);
            }
            if (j == 0) out[tm1] = o;
        }
    };

    auto full_step = [&](float zxv, int t) {
        float z1 = l1_z();       // reads OLD ph0, ph1
        l0_step(zxv);            // updates ph0, c0
        l1_fin(z1, t - 1);       // updates ph1, c1; emits h1(t-1)
    };

    if constexpr (USE_WS) {
        f32x4 cur = zx4[jj];                 // block 0
        f32x4 nxt = zx4[G4 + jj];            // block 1
        f32x4 fut = zx4[2 * G4 + jj];        // block 2
        l0_step(cur.x);                      // t = 0
        full_step(cur.y, 1);
        full_step(cur.z, 2);
        full_step(cur.w, 3);
        for (int b = 1; b < NB; ++b) {
            cur = nxt;
            nxt = fut;
            fut = zx4[(b + 2) * G4 + jj];    // pads exist through block NB+1
            int t = 4 * b;
            full_step(cur.x, t);
            full_step(cur.y, t + 1);
            full_step(cur.z, t + 2);
            full_step(cur.w, t + 3);
        }
        float z1 = l1_z();
        l1_fin(z1, SEQ - 1);
    } else {
        l0_step(xpart(0));
        for (int t = 1; t < SEQ; ++t) full_step(xpart(t), t);
        float z1 = l1_z();
        l1_fin(z1, SEQ - 1);
    }
}

// ---------------------------------------------------------------------------
// Kernel 3: FC head, parallel over t: out[t] = bfc + Wfc . h1(t)
// ---------------------------------------------------------------------------
__global__ __launch_bounds__(256) void fc_head(
    const float* __restrict__ hbuf,
    const float* __restrict__ Wfc,
    const float* __restrict__ bfc,
    float* __restrict__ out)
{
    int t = blockIdx.x * blockDim.x + threadIdx.x;
    if (t >= SEQ) return;
    float o = bfc[0];
    const float* h = hbuf + t * HID;
    #pragma unroll
    for (int kk = 0; kk < HID; ++kk) o = fmaf(Wfc[kk], h[kk], o);
    out[t] = o;
}

extern "C" void kernel_launch(void* const* d_in, const int* in_sizes, int n_in,
                              void* d_out, int out_size, void* d_ws, size_t ws_size,
                              hipStream_t stream) {
    const float* X    = (const float*)d_in[0];
    const float* Wih0 = (const float*)d_in[1];
    const float* Whh0 = (const float*)d_in[2];
    const float* bih0 = (const float*)d_in[3];
    const float* bhh0 = (const float*)d_in[4];
    const float* Wih1 = (const float*)d_in[5];
    const float* Whh1 = (const float*)d_in[6];
    const float* bih1 = (const float*)d_in[7];
    const float* bhh1 = (const float*)d_in[8];
    const float* Wfc  = (const float*)d_in[9];
    const float* bfc  = (const float*)d_in[10];
    float* out = (float*)d_out;

    const size_t zx_floats = (size_t)(NB + 2) * 192;
    const size_t need = (zx_floats + (size_t)SEQ * HID) * sizeof(float);
    if (ws_size >= need) {
        float* zbuf = (float*)d_ws;
        float* hbuf = zbuf + zx_floats;
        lstm_pre<<<((NB + 2) * 192 + 255) / 256, 256, 0, stream>>>(
            X, Wih0, bih0, bhh0, zbuf);
        lstm_seq<true><<<1, 64, 0, stream>>>(
            (const f32x4*)zbuf, hbuf, X, Wih0, bih0, bhh0, Whh0,
            Wih1, Whh1, bih1, bhh1, Wfc, bfc, out);
        fc_head<<<(SEQ + 255) / 256, 256, 0, stream>>>(hbuf, Wfc, bfc, out);
    } else {
        lstm_seq<false><<<1, 64, 0, stream>>>(
            nullptr, nullptr, X, Wih0, bih0, bhh0, Whh0,
            Wih1, Whh1, bih1, bhh1, Wfc, bfc, out);
    }
}

// Round 4
// 155.438 us; speedup vs baseline: 4.5347x; 1.3550x over previous
//
#include <hip/hip_runtime.h>

#define SEQ    1024
#define NBATCH 2048
#define INDIM  32
#define HID    12
#define G4     48          // 4*HID
#define NB     (SEQ / 4)   // float4 blocks of 4 timesteps
#define CHUNK  16
#define NCH    (SEQ / CHUNK)

#define LOG2E 1.4426950408889634f

typedef float f32x2 __attribute__((ext_vector_type(2)));
typedef float f32x4 __attribute__((ext_vector_type(4)));

// ---- low-latency cross-lane primitives ------------------------------------
template<int CTRL>
__device__ __forceinline__ float qbcast(float v) {
    int x = __builtin_amdgcn_update_dpp(
        0, __builtin_bit_cast(int, v), CTRL, 0xF, 0xF, true);
    return __builtin_bit_cast(float, x);
}
__device__ __forceinline__ float lanebcast(float v, int lane) {
    return __builtin_bit_cast(float,
        __builtin_amdgcn_readlane(__builtin_bit_cast(int, v), lane));
}

// ---------------------------------------------------------------------------
// Kernel 1: layer-0 x-part, bias folded, PRE-SCALED by the exp2 gate constant
// cexp(g) (so the seq kernel's z accumulates directly in exp2 domain):
//   zx[b*192 + j*4 + q] = cexp(g) * (b[r] + Wih0[r,:]·X[t,2047,:]),
//   t = 4b+q, j = 4*k+g, r = g*12+k.
// ---------------------------------------------------------------------------
__global__ __launch_bounds__(256) void lstm_pre(
    const float* __restrict__ X,
    const float* __restrict__ Wih0,
    const float* __restrict__ bih0,
    const float* __restrict__ bhh0,
    float* __restrict__ zx)
{
    int idx = blockIdx.x * blockDim.x + threadIdx.x;   // 0 .. (NB+2)*192-1
    if (idx >= (NB + 2) * 192) return;
    int b   = idx / 192;
    int rem = idx - b * 192;
    int j   = rem >> 2;
    int q   = rem & 3;
    int t   = 4 * b + q;
    if (t >= SEQ) { zx[idx] = 0.0f; return; }
    int g = j & 3, k = j >> 2;
    int r = g * HID + k;
    const float cexpg = (g == 2) ? (-2.0f * LOG2E) : (-LOG2E);
    const float* x = X + (size_t)t * NBATCH * INDIM + (size_t)(NBATCH - 1) * INDIM;
    const float* w = Wih0 + r * INDIM;
    float za = bih0[r] + bhh0[r], zb = 0.0f;
    #pragma unroll
    for (int kk = 0; kk < INDIM; kk += 2) {
        za = fmaf(w[kk],     x[kk],     za);
        zb = fmaf(w[kk + 1], x[kk + 1], zb);
    }
    zx[idx] = (za + zb) * cexpg;
}

// ---------------------------------------------------------------------------
// Kernel 2: two-wave pipelined LSTM. Wave 0 = layer 0 producer (h0 -> LDS),
// wave 1 = layer 1 consumer (reads h0 from LDS, writes h1 -> hbuf global).
// Chunked handoff via a monotone done-counter (release/acquire, wg scope).
// ---------------------------------------------------------------------------
__global__ __launch_bounds__(128) void lstm_seq2(
    const f32x4* __restrict__ zx4,     // [(NB+2)][48] float4, pre-scaled
    float* __restrict__ hbuf,          // [SEQ][12] h1 per step
    const float* __restrict__ Whh0,
    const float* __restrict__ Wih1,
    const float* __restrict__ Whh1,
    const float* __restrict__ bih1,
    const float* __restrict__ bhh1)
{
    __shared__ alignas(16) float lds_h0[(SEQ + 4) * HID];
    __shared__ int done;

    const int tid  = threadIdx.x;
    const int wave = tid >> 6;
    const int lane = tid & 63;
    const int jj = (lane < G4) ? lane : 0;
    const int g  = jj & 3;                 // gate: 0=i 1=f 2=g 3=o
    const int k  = jj >> 2;                // hidden unit
    const int r  = g * HID + k;            // weight row
    const float cexp = (g == 2) ? (-2.0f * LOG2E) : (-LOG2E);

    if (tid == 0) done = 0;
    __syncthreads();

    if (wave == 0) {
        // =================== WAVE A: layer 0 ===================
        if (lane < 4 * HID) lds_h0[SEQ * HID + lane] = 0.0f;   // zero pad rows

        f32x2 wh0[HID / 2];
        #pragma unroll
        for (int kk = 0; kk < HID / 2; ++kk)
            wh0[kk] = f32x2{Whh0[r * HID + 2 * kk] * cexp,
                            Whh0[r * HID + 2 * kk + 1] * cexp};

        f32x2 ph0[HID / 2];
        #pragma unroll
        for (int kk = 0; kk < HID / 2; ++kk) ph0[kk] = f32x2{0.f, 0.f};
        float c0 = 0.0f;

        auto step = [&](float zs, int t) {   // zs pre-scaled by cexp
            f32x2 a0 = f32x2{zs, 0.f}, a1 = f32x2{0.f, 0.f};
            #pragma unroll
            for (int kk = 0; kk < HID / 2; kk += 2) {
                a0 = __builtin_elementwise_fma(wh0[kk],     ph0[kk],     a0);
                a1 = __builtin_elementwise_fma(wh0[kk + 1], ph0[kk + 1], a1);
            }
            float z  = (a0.x + a1.x) + (a0.y + a1.y);      // already scaled
            float e  = __builtin_amdgcn_exp2f(z);
            float rr = __builtin_amdgcn_rcpf(1.0f + e);
            float ai = qbcast<0x00>(rr);
            float af = qbcast<0x55>(rr);
            float ag = qbcast<0xAA>(rr);      // sigmoid(2 z_g); tanh = 2ag-1
            float ao = qbcast<0xFF>(rr);
            c0 = fmaf(af, c0, fmaf(ai + ai, ag, -ai));
            float e2 = __builtin_amdgcn_exp2f(c0 * (-2.0f * LOG2E));
            float rt = __builtin_amdgcn_rcpf(1.0f + e2);
            float h0 = fmaf(ao + ao, rt, -ao);             // o * tanh(c0)
            if (lane < G4 && g == 0) lds_h0[t * HID + k] = h0;
            #pragma unroll
            for (int kk = 0; kk < HID / 2; ++kk) {
                ph0[kk].x = lanebcast(h0, 8 * kk);
                ph0[kk].y = lanebcast(h0, 8 * kk + 4);
            }
        };

        f32x4 cur = zx4[jj];
        f32x4 nxt = zx4[G4 + jj];
        f32x4 fut = zx4[2 * G4 + jj];
        step(cur.x, 0); step(cur.y, 1); step(cur.z, 2); step(cur.w, 3);
        for (int b = 1; b < NB; ++b) {
            cur = nxt; nxt = fut;
            fut = zx4[(b + 2) * G4 + jj];
            int t = 4 * b;
            step(cur.x, t); step(cur.y, t + 1);
            step(cur.z, t + 2); step(cur.w, t + 3);
            if ((b & 3) == 3)
                __hip_atomic_store(&done, (b >> 2) + 1,
                                   __ATOMIC_RELEASE, __HIP_MEMORY_SCOPE_WORKGROUP);
        }
    } else {
        // =================== WAVE B: layer 1 ===================
        f32x2 wi1[HID / 2], wh1[HID / 2];
        #pragma unroll
        for (int kk = 0; kk < HID / 2; ++kk) {
            wi1[kk] = f32x2{Wih1[r * HID + 2 * kk] * cexp,
                            Wih1[r * HID + 2 * kk + 1] * cexp};
            wh1[kk] = f32x2{Whh1[r * HID + 2 * kk] * cexp,
                            Whh1[r * HID + 2 * kk + 1] * cexp};
        }
        const float b1s = (bih1[r] + bhh1[r]) * cexp;

        f32x2 ph1[HID / 2];
        #pragma unroll
        for (int kk = 0; kk < HID / 2; ++kk) ph1[kk] = f32x2{0.f, 0.f};
        float c1 = 0.0f;

        auto l1z = [&](const f32x2* h0c) {
            f32x2 a0 = f32x2{b1s, 0.f}, a1 = f32x2{0.f, 0.f};
            f32x2 a2 = f32x2{0.f, 0.f},  a3 = f32x2{0.f, 0.f};
            #pragma unroll
            for (int kk = 0; kk < HID / 2; kk += 2) {
                a0 = __builtin_elementwise_fma(wi1[kk],     h0c[kk],     a0);
                a1 = __builtin_elementwise_fma(wi1[kk + 1], h0c[kk + 1], a1);
                a2 = __builtin_elementwise_fma(wh1[kk],     ph1[kk],     a2);
                a3 = __builtin_elementwise_fma(wh1[kk + 1], ph1[kk + 1], a3);
            }
            f32x2 s = (a0 + a1) + (a2 + a3);
            return s.x + s.y;
        };

        auto l1fin = [&](float z1, int t) {
            float e  = __builtin_amdgcn_exp2f(z1);
            float rr = __builtin_amdgcn_rcpf(1.0f + e);
            float ai = qbcast<0x00>(rr);
            float af = qbcast<0x55>(rr);
            float ag = qbcast<0xAA>(rr);
            float ao = qbcast<0xFF>(rr);
            c1 = fmaf(af, c1, fmaf(ai + ai, ag, -ai));
            float e2 = __builtin_amdgcn_exp2f(c1 * (-2.0f * LOG2E));
            float rt = __builtin_amdgcn_rcpf(1.0f + e2);
            float h1 = fmaf(ao + ao, rt, -ao);
            if (lane < G4 && g == 0) hbuf[t * HID + k] = h1;
            #pragma unroll
            for (int kk = 0; kk < HID / 2; ++kk) {
                ph1[kk].x = lanebcast(h1, 8 * kk);
                ph1[kk].y = lanebcast(h1, 8 * kk + 4);
            }
        };

        auto ldsld = [&](int t, f32x2* dst) {
            #pragma unroll
            for (int kk = 0; kk < HID / 2; ++kk)
                dst[kk] = *reinterpret_cast<const f32x2*>(&lds_h0[t * HID + 2 * kk]);
        };

        int seen = 0;
        do {
            seen = __hip_atomic_load(&done, __ATOMIC_ACQUIRE,
                                     __HIP_MEMORY_SCOPE_WORKGROUP);
        } while (seen < 2);

        f32x2 cA[HID / 2], cB[HID / 2], nA[HID / 2], nBv[HID / 2];
        ldsld(0, cA);
        ldsld(1, cB);

        for (int c = 0; c < NCH; ++c) {
            int need = (c + 2 < NCH) ? (c + 2) : NCH;
            if (seen < need) {
                do {
                    __builtin_amdgcn_s_sleep(2);
                    seen = __hip_atomic_load(&done, __ATOMIC_ACQUIRE,
                                             __HIP_MEMORY_SCOPE_WORKGROUP);
                } while (seen < need);
            }
            int t0 = c * CHUNK;
            #pragma unroll
            for (int p = 0; p < CHUNK / 2; ++p) {
                int t = t0 + 2 * p;
                float z1a = l1z(cA);
                ldsld(t + 2, nA);      // prefetch (valid: chunk c+1 done / pad)
                l1fin(z1a, t);
                float z1b = l1z(cB);
                ldsld(t + 3, nBv);
                l1fin(z1b, t + 1);
                #pragma unroll
                for (int kk = 0; kk < HID / 2; ++kk) { cA[kk] = nA[kk]; cB[kk] = nBv[kk]; }
            }
        }
    }
}

// ---------------------------------------------------------------------------
// Kernel 3: FC head, parallel over t: out[t] = bfc + Wfc . h1(t)
// ---------------------------------------------------------------------------
__global__ __launch_bounds__(256) void fc_head(
    const float* __restrict__ hbuf,
    const float* __restrict__ Wfc,
    const float* __restrict__ bfc,
    float* __restrict__ out)
{
    int t = blockIdx.x * blockDim.x + threadIdx.x;
    if (t >= SEQ) return;
    float o = bfc[0];
    const float* h = hbuf + t * HID;
    #pragma unroll
    for (int kk = 0; kk < HID; ++kk) o = fmaf(Wfc[kk], h[kk], o);
    out[t] = o;
}

// ---------------------------------------------------------------------------
// Fallback (no workspace): single-wave full computation, inline FC.
// ---------------------------------------------------------------------------
__global__ __launch_bounds__(64) void lstm_seq_fb(
    const float* __restrict__ X,
    const float* __restrict__ Wih0,
    const float* __restrict__ bih0,
    const float* __restrict__ bhh0,
    const float* __restrict__ Whh0,
    const float* __restrict__ Wih1,
    const float* __restrict__ Whh1,
    const float* __restrict__ bih1,
    const float* __restrict__ bhh1,
    const float* __restrict__ Wfc,
    const float* __restrict__ bfc,
    float* __restrict__ out)
{
    const int j  = threadIdx.x;
    const int jj = (j < G4) ? j : 0;
    const int g  = jj & 3;
    const int k  = jj >> 2;
    const int r  = g * HID + k;
    const float cexp = (g == 2) ? (-2.0f * LOG2E) : (-LOG2E);

    float whh0[HID], wih1[HID], whh1[HID], wih0[INDIM], wfc[HID];
    #pragma unroll
    for (int kk = 0; kk < HID; ++kk) {
        whh0[kk] = Whh0[r * HID + kk] * cexp;
        wih1[kk] = Wih1[r * HID + kk] * cexp;
        whh1[kk] = Whh1[r * HID + kk] * cexp;
        wfc[kk]  = Wfc[kk];
    }
    #pragma unroll
    for (int kk = 0; kk < INDIM; ++kk) wih0[kk] = Wih0[r * INDIM + kk] * cexp;
    const float b0 = (bih0[r] + bhh0[r]) * cexp;
    const float b1 = (bih1[r] + bhh1[r]) * cexp;
    const float bias_fc = bfc[0];

    float h0v[HID], h1v[HID];
    #pragma unroll
    for (int kk = 0; kk < HID; ++kk) { h0v[kk] = 0.0f; h1v[kk] = 0.0f; }
    float c0 = 0.0f, c1 = 0.0f;

    for (int t = 0; t < SEQ; ++t) {
        const float* x = X + (size_t)t * NBATCH * INDIM
                           + (size_t)(NBATCH - 1) * INDIM;
        float z0 = b0;
        #pragma unroll
        for (int kk = 0; kk < INDIM; ++kk) z0 = fmaf(wih0[kk], x[kk], z0);
        #pragma unroll
        for (int kk = 0; kk < HID; ++kk) z0 = fmaf(whh0[kk], h0v[kk], z0);
        float e  = __builtin_amdgcn_exp2f(z0);
        float rr = __builtin_amdgcn_rcpf(1.0f + e);
        float ai = qbcast<0x00>(rr), af = qbcast<0x55>(rr);
        float ag = qbcast<0xAA>(rr), ao = qbcast<0xFF>(rr);
        c0 = fmaf(af, c0, fmaf(ai + ai, ag, -ai));
        float e2 = __builtin_amdgcn_exp2f(c0 * (-2.0f * LOG2E));
        float rt = __builtin_amdgcn_rcpf(1.0f + e2);
        float h0 = fmaf(ao + ao, rt, -ao);
        #pragma unroll
        for (int kk = 0; kk < HID; ++kk) h0v[kk] = lanebcast(h0, 4 * kk);

        float z1 = b1;
        #pragma unroll
        for (int kk = 0; kk < HID; ++kk) {
            z1 = fmaf(wih1[kk], h0v[kk], z1);
            z1 = fmaf(whh1[kk], h1v[kk], z1);
        }
        e  = __builtin_amdgcn_exp2f(z1);
        rr = __builtin_amdgcn_rcpf(1.0f + e);
        ai = qbcast<0x00>(rr); af = qbcast<0x55>(rr);
        ag = qbcast<0xAA>(rr); ao = qbcast<0xFF>(rr);
        c1 = fmaf(af, c1, fmaf(ai + ai, ag, -ai));
        e2 = __builtin_amdgcn_exp2f(c1 * (-2.0f * LOG2E));
        rt = __builtin_amdgcn_rcpf(1.0f + e2);
        float h1 = fmaf(ao + ao, rt, -ao);
        #pragma unroll
        for (int kk = 0; kk < HID; ++kk) h1v[kk] = lanebcast(h1, 4 * kk);

        float o = bias_fc;
        #pragma unroll
        for (int kk = 0; kk < HID; ++kk) o = fmaf(wfc[kk], h1v[kk], o);
        if (j == 0) out[t] = o;
    }
}

extern "C" void kernel_launch(void* const* d_in, const int* in_sizes, int n_in,
                              void* d_out, int out_size, void* d_ws, size_t ws_size,
                              hipStream_t stream) {
    const float* X    = (const float*)d_in[0];
    const float* Wih0 = (const float*)d_in[1];
    const float* Whh0 = (const float*)d_in[2];
    const float* bih0 = (const float*)d_in[3];
    const float* bhh0 = (const float*)d_in[4];
    const float* Wih1 = (const float*)d_in[5];
    const float* Whh1 = (const float*)d_in[6];
    const float* bih1 = (const float*)d_in[7];
    const float* bhh1 = (const float*)d_in[8];
    const float* Wfc  = (const float*)d_in[9];
    const float* bfc  = (const float*)d_in[10];
    float* out = (float*)d_out;

    const size_t zx_floats = (size_t)(NB + 2) * 192;
    const size_t need = (zx_floats + (size_t)SEQ * HID) * sizeof(float);
    if (ws_size >= need) {
        float* zbuf = (float*)d_ws;
        float* hbuf = zbuf + zx_floats;
        lstm_pre<<<((NB + 2) * 192 + 255) / 256, 256, 0, stream>>>(
            X, Wih0, bih0, bhh0, zbuf);
        lstm_seq2<<<1, 128, 0, stream>>>(
            (const f32x4*)zbuf, hbuf, Whh0, Wih1, Whh1, bih1, bhh1);
        fc_head<<<(SEQ + 255) / 256, 256, 0, stream>>>(hbuf, Wfc, bfc, out);
    } else {
        lstm_seq_fb<<<1, 64, 0, stream>>>(
            X, Wih0, bih0, bhh0, Whh0,
            Wih1, Whh1, bih1, bhh1, Wfc, bfc, out);
    }
}

// Round 5
// 153.638 us; speedup vs baseline: 4.5878x; 1.0117x over previous
//
#include <hip/hip_runtime.h>

#define SEQ    1024
#define NBATCH 2048
#define INDIM  32
#define HID    12
#define G4     48          // 4*HID
#define NB     (SEQ / 4)   // float4 blocks of 4 timesteps
#define NBLK   (NB + 4)    // zx blocks incl pad blocks
#define CHUNK  16
#define NCH    (SEQ / CHUNK)

#define LOG2E 1.4426950408889634f

typedef float f32x2 __attribute__((ext_vector_type(2)));
typedef float f32x4 __attribute__((ext_vector_type(4)));

// ---- low-latency cross-lane primitives ------------------------------------
template<int CTRL>
__device__ __forceinline__ float qbcast(float v) {
    int x = __builtin_amdgcn_update_dpp(
        0, __builtin_bit_cast(int, v), CTRL, 0xF, 0xF, true);
    return __builtin_bit_cast(float, x);
}
__device__ __forceinline__ float lanebcast(float v, int lane) {
    return __builtin_bit_cast(float,
        __builtin_amdgcn_readlane(__builtin_bit_cast(int, v), lane));
}
__device__ __forceinline__ float sig_part(float zs) {   // rcp(1 + exp2(zs))
    return __builtin_amdgcn_rcpf(1.0f + __builtin_amdgcn_exp2f(zs));
}

// ---------------------------------------------------------------------------
// Kernel 1: layer-0 x-part, bias folded, PRE-SCALED by cexp(g):
//   zx[b*192 + j*4 + q] = cexp(g) * (b[r] + Wih0[r,:]·X[t,2047,:]),
//   t = 4b+q, j = 4*k+g, r = g*12+k.  Blocks b in [0,NBLK); t>=SEQ zeroed.
// ---------------------------------------------------------------------------
__global__ __launch_bounds__(256) void lstm_pre(
    const float* __restrict__ X,
    const float* __restrict__ Wih0,
    const float* __restrict__ bih0,
    const float* __restrict__ bhh0,
    float* __restrict__ zx)
{
    int idx = blockIdx.x * blockDim.x + threadIdx.x;
    if (idx >= NBLK * 192) return;
    int b   = idx / 192;
    int rem = idx - b * 192;
    int j   = rem >> 2;
    int q   = rem & 3;
    int t   = 4 * b + q;
    if (t >= SEQ) { zx[idx] = 0.0f; return; }
    int g = j & 3, k = j >> 2;
    int r = g * HID + k;
    const float cexpg = (g == 2) ? (-2.0f * LOG2E) : (-LOG2E);
    const float* x = X + (size_t)t * NBATCH * INDIM + (size_t)(NBATCH - 1) * INDIM;
    const float* w = Wih0 + r * INDIM;
    float za = bih0[r] + bhh0[r], zb = 0.0f;
    #pragma unroll
    for (int kk = 0; kk < INDIM; kk += 2) {
        za = fmaf(w[kk],     x[kk],     za);
        zb = fmaf(w[kk + 1], x[kk + 1], zb);
    }
    zx[idx] = (za + zb) * cexpg;
}

// ---------------------------------------------------------------------------
// Kernel 2: two-wave barrier-lockstep pipeline.
// Wave 0 (A): layer 0, produces chunk i at iteration i   -> lds_h0
// Wave 1 (B): layer 1, consumes chunk i-2 at iteration i -> hbuf
// One __syncthreads per iteration; B lags 2 chunks so its 4-step-group
// prefetch (reaching 4 rows into chunk i-1) is always behind a barrier.
// ---------------------------------------------------------------------------
__global__ __launch_bounds__(128) void lstm_seq2(
    const f32x4* __restrict__ zx4,     // [NBLK][48] f32x4, pre-scaled
    float* __restrict__ hbuf,          // [SEQ][12] h1 per step
    const float* __restrict__ Whh0,
    const float* __restrict__ Wih1,
    const float* __restrict__ Whh1,
    const float* __restrict__ bih1,
    const float* __restrict__ bhh1)
{
    __shared__ alignas(16) float lds_h0[(SEQ + 4) * HID];

    const int tid  = threadIdx.x;
    const int wave = tid >> 6;
    const int lane = tid & 63;
    const int jj = (lane < G4) ? lane : 0;
    const int g  = jj & 3;                 // gate: 0=i 1=f 2=g 3=o
    const int k  = jj >> 2;                // hidden unit
    const int r  = g * HID + k;            // weight row
    const float cexp = (g == 2) ? (-2.0f * LOG2E) : (-LOG2E);
    const float TSA = -4.0f * LOG2E;       // igs = ai * fma(TSA, ag, TSB)
    const float TSB =  2.0f * LOG2E;

    // ---- per-wave persistent state (allocated in both, used in one) ----
    f32x4 wh0[3];                 // A: Whh0 row, scaled
    f32x4 zbE[4], zbO[4];         // A: ping-pong zx chunk buffers
    f32x4 ph0[3];  float cs0 = 0.0f;
    f32x4 wi1[3], wh1[3];         // B: layer-1 weight rows, scaled
    f32x4 hb0[4][3], hb1[4][3];   // B: ping-pong h0 group buffers
    f32x4 ph1[3];  float cs1 = 0.0f;
    float b1s = 0.0f;

    #pragma unroll
    for (int m = 0; m < 3; ++m) { ph0[m] = f32x4{0,0,0,0}; ph1[m] = f32x4{0,0,0,0}; }

    if (wave == 0) {
        if (lane < G4) lds_h0[SEQ * HID + lane] = 0.0f;   // zero pad rows
        #pragma unroll
        for (int m = 0; m < 3; ++m)
            wh0[m] = *(const f32x4*)(Whh0 + r * HID + 4 * m) * cexp;
        // prologue: chunk 0 into zbE
        #pragma unroll
        for (int bb = 0; bb < 4; ++bb) zbE[bb] = zx4[bb * G4 + jj];
    } else {
        #pragma unroll
        for (int m = 0; m < 3; ++m) {
            wi1[m] = *(const f32x4*)(Wih1 + r * HID + 4 * m) * cexp;
            wh1[m] = *(const f32x4*)(Whh1 + r * HID + 4 * m) * cexp;
        }
        b1s = (bih1[r] + bhh1[r]) * cexp;
    }
    __syncthreads();

#define STEPA(zs, t) { \
    f32x4 a0 = __builtin_elementwise_fma(wh0[0], ph0[0], f32x4{(zs), 0.f, 0.f, 0.f}); \
    f32x4 a1 = __builtin_elementwise_fma(wh0[1], ph0[1], f32x4{0.f, 0.f, 0.f, 0.f}); \
    f32x4 a2 = __builtin_elementwise_fma(wh0[2], ph0[2], f32x4{0.f, 0.f, 0.f, 0.f}); \
    f32x4 sv = (a0 + a1) + a2; \
    float z  = (sv.x + sv.y) + (sv.z + sv.w); \
    float rr = sig_part(z); \
    float ai = qbcast<0x00>(rr), af = qbcast<0x55>(rr); \
    float ag = qbcast<0xAA>(rr), ao = qbcast<0xFF>(rr); \
    float igs = ai * fmaf(TSA, ag, TSB); \
    cs0 = fmaf(af, cs0, igs); \
    float rt = sig_part(cs0); \
    float h0 = fmaf(ao + ao, rt, -ao); \
    if (lane < G4 && g == 0) lds_h0[(t) * HID + k] = h0; \
    ph0[0] = f32x4{lanebcast(h0, 0),  lanebcast(h0, 4),  lanebcast(h0, 8),  lanebcast(h0, 12)}; \
    ph0[1] = f32x4{lanebcast(h0, 16), lanebcast(h0, 20), lanebcast(h0, 24), lanebcast(h0, 28)}; \
    ph0[2] = f32x4{lanebcast(h0, 32), lanebcast(h0, 36), lanebcast(h0, 40), lanebcast(h0, 44)}; \
}

#define AITER(cur, nxt, ci) { \
    int cb = 4 * ((ci) + 1); \
    nxt[0] = zx4[(cb + 0) * G4 + jj]; \
    nxt[1] = zx4[(cb + 1) * G4 + jj]; \
    nxt[2] = zx4[(cb + 2) * G4 + jj]; \
    nxt[3] = zx4[(cb + 3) * G4 + jj]; \
    int tA = CHUNK * (ci); \
    STEPA(cur[0].x, tA + 0)  STEPA(cur[0].y, tA + 1)  STEPA(cur[0].z, tA + 2)  STEPA(cur[0].w, tA + 3)  \
    STEPA(cur[1].x, tA + 4)  STEPA(cur[1].y, tA + 5)  STEPA(cur[1].z, tA + 6)  STEPA(cur[1].w, tA + 7)  \
    STEPA(cur[2].x, tA + 8)  STEPA(cur[2].y, tA + 9)  STEPA(cur[2].z, tA + 10) STEPA(cur[2].w, tA + 11) \
    STEPA(cur[3].x, tA + 12) STEPA(cur[3].y, tA + 13) STEPA(cur[3].z, tA + 14) STEPA(cur[3].w, tA + 15) \
}

#define LDGRP(trow, dst) { \
    dst[0][0] = *(const f32x4*)&lds_h0[((trow) + 0) * HID + 0]; \
    dst[0][1] = *(const f32x4*)&lds_h0[((trow) + 0) * HID + 4]; \
    dst[0][2] = *(const f32x4*)&lds_h0[((trow) + 0) * HID + 8]; \
    dst[1][0] = *(const f32x4*)&lds_h0[((trow) + 1) * HID + 0]; \
    dst[1][1] = *(const f32x4*)&lds_h0[((trow) + 1) * HID + 4]; \
    dst[1][2] = *(const f32x4*)&lds_h0[((trow) + 1) * HID + 8]; \
    dst[2][0] = *(const f32x4*)&lds_h0[((trow) + 2) * HID + 0]; \
    dst[2][1] = *(const f32x4*)&lds_h0[((trow) + 2) * HID + 4]; \
    dst[2][2] = *(const f32x4*)&lds_h0[((trow) + 2) * HID + 8]; \
    dst[3][0] = *(const f32x4*)&lds_h0[((trow) + 3) * HID + 0]; \
    dst[3][1] = *(const f32x4*)&lds_h0[((trow) + 3) * HID + 4]; \
    dst[3][2] = *(const f32x4*)&lds_h0[((trow) + 3) * HID + 8]; \
}

#define STEPB(cur, qi, t) { \
    f32x4 a0 = __builtin_elementwise_fma(wi1[0], cur[qi][0], f32x4{b1s, 0.f, 0.f, 0.f}); \
    f32x4 a1 = __builtin_elementwise_fma(wi1[1], cur[qi][1], f32x4{0.f, 0.f, 0.f, 0.f}); \
    f32x4 a2 = __builtin_elementwise_fma(wi1[2], cur[qi][2], f32x4{0.f, 0.f, 0.f, 0.f}); \
    a0 = __builtin_elementwise_fma(wh1[0], ph1[0], a0); \
    a1 = __builtin_elementwise_fma(wh1[1], ph1[1], a1); \
    a2 = __builtin_elementwise_fma(wh1[2], ph1[2], a2); \
    f32x4 sv = (a0 + a1) + a2; \
    float z  = (sv.x + sv.y) + (sv.z + sv.w); \
    float rr = sig_part(z); \
    float ai = qbcast<0x00>(rr), af = qbcast<0x55>(rr); \
    float ag = qbcast<0xAA>(rr), ao = qbcast<0xFF>(rr); \
    float igs = ai * fmaf(TSA, ag, TSB); \
    cs1 = fmaf(af, cs1, igs); \
    float rt = sig_part(cs1); \
    float h1 = fmaf(ao + ao, rt, -ao); \
    if (lane < G4 && g == 0) hbuf[(t) * HID + k] = h1; \
    ph1[0] = f32x4{lanebcast(h1, 0),  lanebcast(h1, 4),  lanebcast(h1, 8),  lanebcast(h1, 12)}; \
    ph1[1] = f32x4{lanebcast(h1, 16), lanebcast(h1, 20), lanebcast(h1, 24), lanebcast(h1, 28)}; \
    ph1[2] = f32x4{lanebcast(h1, 32), lanebcast(h1, 36), lanebcast(h1, 40), lanebcast(h1, 44)}; \
}

#define BGRP(cur, nxt, tload, tproc) { \
    LDGRP((tload), nxt) \
    STEPB(cur, 0, (tproc) + 0) STEPB(cur, 1, (tproc) + 1) \
    STEPB(cur, 2, (tproc) + 2) STEPB(cur, 3, (tproc) + 3) \
}

    for (int i = 0; i < NCH + 2; ++i) {
        if (wave == 0) {
            if (i < NCH) {
                if ((i & 1) == 0) { AITER(zbE, zbO, i) }
                else              { AITER(zbO, zbE, i) }
            }
        } else {
            if (i >= 2) {
                int t0 = (i - 2) * CHUNK;
                if (i == 2) { LDGRP(0, hb0) }
                BGRP(hb0, hb1, t0 + 4,  t0)
                BGRP(hb1, hb0, t0 + 8,  t0 + 4)
                BGRP(hb0, hb1, t0 + 12, t0 + 8)
                BGRP(hb1, hb0, t0 + 16, t0 + 12)
            }
        }
        __syncthreads();
    }
#undef STEPA
#undef AITER
#undef LDGRP
#undef STEPB
#undef BGRP
}

// ---------------------------------------------------------------------------
// Kernel 3: FC head, parallel over t: out[t] = bfc + Wfc . h1(t)
// ---------------------------------------------------------------------------
__global__ __launch_bounds__(256) void fc_head(
    const float* __restrict__ hbuf,
    const float* __restrict__ Wfc,
    const float* __restrict__ bfc,
    float* __restrict__ out)
{
    int t = blockIdx.x * blockDim.x + threadIdx.x;
    if (t >= SEQ) return;
    float o = bfc[0];
    const float* h = hbuf + t * HID;
    #pragma unroll
    for (int kk = 0; kk < HID; ++kk) o = fmaf(Wfc[kk], h[kk], o);
    out[t] = o;
}

// ---------------------------------------------------------------------------
// Fallback (no workspace): single-wave full computation, inline FC.
// ---------------------------------------------------------------------------
__global__ __launch_bounds__(64) void lstm_seq_fb(
    const float* __restrict__ X,
    const float* __restrict__ Wih0,
    const float* __restrict__ bih0,
    const float* __restrict__ bhh0,
    const float* __restrict__ Whh0,
    const float* __restrict__ Wih1,
    const float* __restrict__ Whh1,
    const float* __restrict__ bih1,
    const float* __restrict__ bhh1,
    const float* __restrict__ Wfc,
    const float* __restrict__ bfc,
    float* __restrict__ out)
{
    const int j  = threadIdx.x;
    const int jj = (j < G4) ? j : 0;
    const int g  = jj & 3;
    const int k  = jj >> 2;
    const int r  = g * HID + k;
    const float cexp = (g == 2) ? (-2.0f * LOG2E) : (-LOG2E);
    const float TSA = -4.0f * LOG2E;
    const float TSB =  2.0f * LOG2E;

    float whh0[HID], wih1[HID], whh1[HID], wih0[INDIM], wfc[HID];
    #pragma unroll
    for (int kk = 0; kk < HID; ++kk) {
        whh0[kk] = Whh0[r * HID + kk] * cexp;
        wih1[kk] = Wih1[r * HID + kk] * cexp;
        whh1[kk] = Whh1[r * HID + kk] * cexp;
        wfc[kk]  = Wfc[kk];
    }
    #pragma unroll
    for (int kk = 0; kk < INDIM; ++kk) wih0[kk] = Wih0[r * INDIM + kk] * cexp;
    const float b0 = (bih0[r] + bhh0[r]) * cexp;
    const float b1 = (bih1[r] + bhh1[r]) * cexp;
    const float bias_fc = bfc[0];

    float h0v[HID], h1v[HID];
    #pragma unroll
    for (int kk = 0; kk < HID; ++kk) { h0v[kk] = 0.0f; h1v[kk] = 0.0f; }
    float cs0 = 0.0f, cs1 = 0.0f;

    for (int t = 0; t < SEQ; ++t) {
        const float* x = X + (size_t)t * NBATCH * INDIM
                           + (size_t)(NBATCH - 1) * INDIM;
        float z0 = b0;
        #pragma unroll
        for (int kk = 0; kk < INDIM; ++kk) z0 = fmaf(wih0[kk], x[kk], z0);
        #pragma unroll
        for (int kk = 0; kk < HID; ++kk) z0 = fmaf(whh0[kk], h0v[kk], z0);
        float rr = sig_part(z0);
        float ai = qbcast<0x00>(rr), af = qbcast<0x55>(rr);
        float ag = qbcast<0xAA>(rr), ao = qbcast<0xFF>(rr);
        cs0 = fmaf(af, cs0, ai * fmaf(TSA, ag, TSB));
        float rt = sig_part(cs0);
        float h0 = fmaf(ao + ao, rt, -ao);
        #pragma unroll
        for (int kk = 0; kk < HID; ++kk) h0v[kk] = lanebcast(h0, 4 * kk);

        float z1 = b1;
        #pragma unroll
        for (int kk = 0; kk < HID; ++kk) {
            z1 = fmaf(wih1[kk], h0v[kk], z1);
            z1 = fmaf(whh1[kk], h1v[kk], z1);
        }
        rr = sig_part(z1);
        ai = qbcast<0x00>(rr); af = qbcast<0x55>(rr);
        ag = qbcast<0xAA>(rr); ao = qbcast<0xFF>(rr);
        cs1 = fmaf(af, cs1, ai * fmaf(TSA, ag, TSB));
        rt = sig_part(cs1);
        float h1 = fmaf(ao + ao, rt, -ao);
        #pragma unroll
        for (int kk = 0; kk < HID; ++kk) h1v[kk] = lanebcast(h1, 4 * kk);

        float o = bias_fc;
        #pragma unroll
        for (int kk = 0; kk < HID; ++kk) o = fmaf(wfc[kk], h1v[kk], o);
        if (j == 0) out[t] = o;
    }
}

extern "C" void kernel_launch(void* const* d_in, const int* in_sizes, int n_in,
                              void* d_out, int out_size, void* d_ws, size_t ws_size,
                              hipStream_t stream) {
    const float* X    = (const float*)d_in[0];
    const float* Wih0 = (const float*)d_in[1];
    const float* Whh0 = (const float*)d_in[2];
    const float* bih0 = (const float*)d_in[3];
    const float* bhh0 = (const float*)d_in[4];
    const float* Wih1 = (const float*)d_in[5];
    const float* Whh1 = (const float*)d_in[6];
    const float* bih1 = (const float*)d_in[7];
    const float* bhh1 = (const float*)d_in[8];
    const float* Wfc  = (const float*)d_in[9];
    const float* bfc  = (const float*)d_in[10];
    float* out = (float*)d_out;

    const size_t zx_floats = (size_t)NBLK * 192;
    const size_t need = (zx_floats + (size_t)SEQ * HID) * sizeof(float);
    if (ws_size >= need) {
        float* zbuf = (float*)d_ws;
        float* hbuf = zbuf + zx_floats;
        lstm_pre<<<(NBLK * 192 + 255) / 256, 256, 0, stream>>>(
            X, Wih0, bih0, bhh0, zbuf);
        lstm_seq2<<<1, 128, 0, stream>>>(
            (const f32x4*)zbuf, hbuf, Whh0, Wih1, Whh1, bih1, bhh1);
        fc_head<<<(SEQ + 255) / 256, 256, 0, stream>>>(hbuf, Wfc, bfc, out);
    } else {
        lstm_seq_fb<<<1, 64, 0, stream>>>(
            X, Wih0, bih0, bhh0, Whh0,
            Wih1, Whh1, bih1, bhh1, Wfc, bfc, out);
    }
}